// Round 4
// baseline (1476.835 us; speedup 1.0000x reference)
//
#include <hip/hip_runtime.h>
#include <hip/hip_bf16.h>

typedef __attribute__((ext_vector_type(8))) short short8;
typedef __attribute__((ext_vector_type(4))) float floatx4;
typedef __attribute__((ext_vector_type(4))) unsigned short ushortx4;

typedef __attribute__((address_space(3))) unsigned int lds_u32;
typedef __attribute__((address_space(1))) const unsigned int g_u32;

__device__ __forceinline__ float bf2f(unsigned short u) {
    union { float f; unsigned int i; } v; v.i = ((unsigned int)u) << 16; return v.f;
}
__device__ __forceinline__ unsigned short f2bf(float f) {
    union { float f; unsigned int i; } v; v.f = f;
    unsigned int r = v.i + 0x7fffu + ((v.i >> 16) & 1u);
    return (unsigned short)(r >> 16);
}

// ---------------------------------------------------------------------------
// CSR build: degree histogram -> chunked block scan -> scatter.
// ---------------------------------------------------------------------------
__global__ void deg_count(const int* __restrict__ dst, int* __restrict__ deg, int E) {
    int i = blockIdx.x * 256 + threadIdx.x;
    if (i < E) atomicAdd(&deg[dst[i]], 1);
}

__global__ __launch_bounds__(1024) void scan_rowptr(const int* __restrict__ deg,
                                                    int* __restrict__ rowptr,
                                                    int* __restrict__ cursor, int N) {
    const int CH = 20;  // 1024*20 = 20480 >= N
    __shared__ int buf[1024];
    int t = threadIdx.x;
    int base = t * CH;
    int local[CH];
    int tot = 0;
#pragma unroll
    for (int k = 0; k < CH; ++k) {
        int i = base + k;
        int v = (i < N) ? deg[i] : 0;
        local[k] = tot;
        tot += v;
    }
    buf[t] = tot;
    __syncthreads();
    for (int off = 1; off < 1024; off <<= 1) {
        int x = (t >= off) ? buf[t - off] : 0;
        __syncthreads();
        buf[t] += x;
        __syncthreads();
    }
    int excl = buf[t] - tot;
#pragma unroll
    for (int k = 0; k < CH; ++k) {
        int i = base + k;
        if (i < N) { rowptr[i] = excl + local[k]; cursor[i] = excl + local[k]; }
    }
    if (t == 1023) rowptr[N] = buf[1023];
}

__global__ void scatter_edges(const int* __restrict__ src, const int* __restrict__ dst,
                              int* __restrict__ cursor, int* __restrict__ eix,
                              int* __restrict__ sx, int* __restrict__ dstx, int E) {
    int i = blockIdx.x * 256 + threadIdx.x;
    if (i >= E) return;
    int d = dst[i];
    int pos = atomicAdd(&cursor[d], 1);
    eix[pos] = i;
    sx[pos] = src[i];
    dstx[pos] = d;
}

// ---------------------------------------------------------------------------
// Weight pre-transpose + bf16 convert: Wt[slot][n*128+k] = bf16(W[slot][k*128+n])
// ---------------------------------------------------------------------------
__global__ void transpose_w(const float* __restrict__ Wh,
                            const float* __restrict__ We,
                            const float* __restrict__ Aw,
                            const float* __restrict__ Bw,
                            const float* __restrict__ Cw,
                            const float* __restrict__ Dw,
                            const float* __restrict__ Ew,
                            unsigned short* __restrict__ Wt) {
    int i = blockIdx.x * 256 + threadIdx.x;
    const int total = 22 * 16384;
    if (i >= total) return;
    int slot = i >> 14;
    int r = i & 16383;
    int n = r >> 7;
    int k = r & 127;
    const float* srcp;
    if (slot == 0) srcp = Wh;
    else if (slot == 1) srcp = We;
    else {
        int t = slot - 2;
        int l = t / 5, w = t % 5;
        const float* bases[5] = {Aw, Bw, Cw, Dw, Ew};
        srcp = bases[w] + l * 16384;
    }
    Wt[i] = f2bf(srcp[k * 128 + n]);
}

// ---------------------------------------------------------------------------
// LDS-staged streaming GEMM (embeddings): C[M,128] = A[M,128]@W + bias.
// ---------------------------------------------------------------------------
template <int IN_F32, int OUT_BF16, int GATHER>
__global__ __launch_bounds__(256) void gemm_lds(const void* __restrict__ Ain,
                                                const int* __restrict__ ridx,
                                                const unsigned short* __restrict__ Wt,
                                                const float* __restrict__ bias,
                                                void* __restrict__ Cout,
                                                int nTiles, int Mrows) {
    constexpr int ROWB = IN_F32 ? 512 : 256;     // bytes per row
    constexpr int RSH = IN_F32 ? 9 : 8;
    constexpr int TILEB = 64 * ROWB;             // 32KB / 16KB
    constexpr int PERW = TILEB / 4;              // bytes staged per wave
    constexpr int ROUNDS = PERW / 1024;          // gl_lds insts per wave
    __shared__ unsigned char smem[2][TILEB];

    const int lane = threadIdx.x & 63;
    const int wv = threadIdx.x >> 6;
    const int m16 = lane & 15;
    const int kg = lane >> 4;

    short8 b[4][2];
#pragma unroll
    for (int j = 0; j < 2; ++j)
#pragma unroll
        for (int ks = 0; ks < 4; ++ks)
            b[ks][j] = *(const short8*)(Wt + ((wv * 2 + j) * 16 + m16) * 128 + ks * 32 + kg * 8);
    floatx4 bv[2];
#pragma unroll
    for (int j = 0; j < 2; ++j)
        bv[j] = *(const floatx4*)(bias + (wv * 2 + j) * 16 + kg * 4);

    const unsigned char* Ab = (const unsigned char*)Ain;

    int t0 = blockIdx.x;
    if (t0 >= nTiles) return;

    auto stage = [&](int bufsel, int t) {
#pragma unroll
        for (int r = 0; r < ROUNDS; ++r) {
            int d = wv * PERW + r * 1024 + lane * 16;   // linear dest byte in tile
            int row = d >> RSH;
            int scol;
            if (IN_F32)
                scol = (d ^ ((row & 3) << 5)) & (ROWB - 1);
            else
                scol = (d ^ ((row & 7) << 4)) & (ROWB - 1);
            int grow = t * 64 + row;
            grow = grow < Mrows ? grow : Mrows - 1;     // clamp tail (h path)
            if (GATHER) grow = ridx[grow];
            const unsigned char* gp = Ab + (size_t)grow * ROWB + scol;
            unsigned char* lp = &smem[bufsel][wv * PERW + r * 1024];  // wave-uniform
            __builtin_amdgcn_global_load_lds((g_u32*)gp, (lds_u32*)lp, 16, 0, 0);
        }
    };

    int cur = 0;
    stage(0, t0);
    __syncthreads();

    for (int t = t0; t < nTiles; t += gridDim.x) {
        int tn = t + gridDim.x;
        if (tn < nTiles) stage(cur ^ 1, tn);   // prefetch overlaps compute

        const unsigned char* sb = smem[cur];
#pragma unroll
        for (int st = 0; st < 4; ++st) {
            short8 a[4];
#pragma unroll
            for (int ks = 0; ks < 4; ++ks) {
                if (IN_F32) {
                    int aoff = (st * 16 + m16) * 512 + ks * 128 + kg * 32;
                    aoff ^= (m16 & 3) << 5;
                    floatx4 f0 = *(const floatx4*)(sb + aoff);
                    floatx4 f1 = *(const floatx4*)(sb + aoff + 16);
                    short8 tt;
                    tt[0] = (short)f2bf(f0[0]); tt[1] = (short)f2bf(f0[1]);
                    tt[2] = (short)f2bf(f0[2]); tt[3] = (short)f2bf(f0[3]);
                    tt[4] = (short)f2bf(f1[0]); tt[5] = (short)f2bf(f1[1]);
                    tt[6] = (short)f2bf(f1[2]); tt[7] = (short)f2bf(f1[3]);
                    a[ks] = tt;
                } else {
                    int aoff = (st * 16 + m16) * 256 + ks * 64 + kg * 16;
                    aoff ^= (m16 & 7) << 4;
                    a[ks] = *(const short8*)(sb + aoff);
                }
            }
            floatx4 acc0 = (floatx4){0.f, 0.f, 0.f, 0.f};
            floatx4 acc1 = (floatx4){0.f, 0.f, 0.f, 0.f};
#pragma unroll
            for (int ks = 0; ks < 4; ++ks) {
                acc0 = __builtin_amdgcn_mfma_f32_16x16x32_bf16(b[ks][0], a[ks], acc0, 0, 0, 0);
                acc1 = __builtin_amdgcn_mfma_f32_16x16x32_bf16(b[ks][1], a[ks], acc1, 0, 0, 0);
            }
            size_t row = (size_t)t * 64 + st * 16 + m16;
#pragma unroll
            for (int j = 0; j < 2; ++j) {
                int c0 = (wv * 2 + j) * 16 + kg * 4;
                floatx4 accj = j ? acc1 : acc0;
                if (OUT_BF16) {
                    ushortx4 o;
#pragma unroll
                    for (int i = 0; i < 4; ++i) o[i] = f2bf(accj[i] + bv[j][i]);
                    *(ushortx4*)((unsigned short*)Cout + row * 128 + c0) = o;
                } else {
                    floatx4 o;
#pragma unroll
                    for (int i = 0; i < 4; ++i) o[i] = accj[i] + bv[j][i];
                    *(floatx4*)((float*)Cout + row * 128 + c0) = o;
                }
            }
        }
        __syncthreads();   // drains DMA for next buf + orders LDS reuse
        cur ^= 1;
    }
}

// ---------------------------------------------------------------------------
// Fully-fused edge kernel: e_new = e_cur@Cw + Cb + Dh[sx] + Eh[dstx];
// sigma = sigmoid(e_new); per-dst num/den accumulated via 16-lane SEGMENTED
// SCAN over the CSR-contiguous edges held by m16 lanes, run-tail lanes
// atomicAdd into num/den[dst]. e-BN stats in registers (STATS). Gathers
// (Dh/Eh/Bh, L2-resident) issued BEFORE LDS reads + MFMA so they drain
// under compute. STATS=0 (last layer) also skips the e_new store.
// ---------------------------------------------------------------------------
template <int STATS>
__global__ __launch_bounds__(256) void gemm_ce(const unsigned short* __restrict__ Ain,
                                               const unsigned short* __restrict__ Wt,
                                               const float* __restrict__ bias,
                                               const int* __restrict__ sx,
                                               const int* __restrict__ dstx,
                                               const unsigned short* __restrict__ Bh16,
                                               const unsigned short* __restrict__ Dh16,
                                               const unsigned short* __restrict__ Eh16,
                                               unsigned short* __restrict__ e_new,
                                               float* __restrict__ num,
                                               float* __restrict__ den,
                                               float* __restrict__ sums,
                                               int nTiles) {
    constexpr int TILEB = 64 * 256;              // 16KB
    constexpr int PERW = TILEB / 4;
    constexpr int ROUNDS = PERW / 1024;
    __shared__ unsigned char smem[2][TILEB];
    __shared__ float ls[256];

    const int lane = threadIdx.x & 63;
    const int wv = threadIdx.x >> 6;
    const int m16 = lane & 15;
    const int kg = lane >> 4;

    short8 b[4][2];
#pragma unroll
    for (int j = 0; j < 2; ++j)
#pragma unroll
        for (int ks = 0; ks < 4; ++ks)
            b[ks][j] = *(const short8*)(Wt + ((wv * 2 + j) * 16 + m16) * 128 + ks * 32 + kg * 8);
    floatx4 bv[2];
#pragma unroll
    for (int j = 0; j < 2; ++j)
        bv[j] = *(const floatx4*)(bias + (wv * 2 + j) * 16 + kg * 4);

    float es[2][4], eq[2][4];
#pragma unroll
    for (int j = 0; j < 2; ++j)
#pragma unroll
        for (int i = 0; i < 4; ++i) { es[j][i] = 0.f; eq[j][i] = 0.f; }

    const unsigned char* Ab = (const unsigned char*)Ain;

    int t0 = blockIdx.x;

    auto stage = [&](int bufsel, int t) {
#pragma unroll
        for (int r = 0; r < ROUNDS; ++r) {
            int d = wv * PERW + r * 1024 + lane * 16;
            int row = d >> 8;
            int scol = (d ^ ((row & 7) << 4)) & 255;
            const unsigned char* gp = Ab + (size_t)(t * 64 + row) * 256 + scol;
            unsigned char* lp = &smem[bufsel][wv * PERW + r * 1024];
            __builtin_amdgcn_global_load_lds((g_u32*)gp, (lds_u32*)lp, 16, 0, 0);
        }
    };

    int cur = 0;
    if (t0 < nTiles) {
        stage(0, t0);
        __syncthreads();

        for (int t = t0; t < nTiles; t += gridDim.x) {
            int tn = t + gridDim.x;
            if (tn < nTiles) stage(cur ^ 1, tn);

            // edge metadata for the whole tile, issued early (coalesced)
            int sxv[4], dxv[4];
#pragma unroll
            for (int st = 0; st < 4; ++st) {
                int erow = t * 64 + st * 16 + m16;
                sxv[st] = sx[erow];
                dxv[st] = dstx[erow];
            }

            const unsigned char* sb = smem[cur];
#pragma unroll
            for (int st = 0; st < 4; ++st) {
                int erow = t * 64 + st * 16 + m16;
                int sr = sxv[st], dr = dxv[st];
                // issue gathers BEFORE LDS reads + MFMA (drain under compute)
                ushortx4 dh[2], eh[2], bh[2];
#pragma unroll
                for (int j = 0; j < 2; ++j) {
                    int c0 = (wv * 2 + j) * 16 + kg * 4;
                    dh[j] = *(const ushortx4*)(Dh16 + (size_t)sr * 128 + c0);
                    eh[j] = *(const ushortx4*)(Eh16 + (size_t)dr * 128 + c0);
                    bh[j] = *(const ushortx4*)(Bh16 + (size_t)sr * 128 + c0);
                }
                short8 a[4];
#pragma unroll
                for (int ks = 0; ks < 4; ++ks) {
                    int aoff = (st * 16 + m16) * 256 + ks * 64 + kg * 16;
                    aoff ^= (m16 & 7) << 4;
                    a[ks] = *(const short8*)(sb + aoff);
                }
                floatx4 acc0 = (floatx4){0.f, 0.f, 0.f, 0.f};
                floatx4 acc1 = (floatx4){0.f, 0.f, 0.f, 0.f};
#pragma unroll
                for (int ks = 0; ks < 4; ++ks) {
                    acc0 = __builtin_amdgcn_mfma_f32_16x16x32_bf16(b[ks][0], a[ks], acc0, 0, 0, 0);
                    acc1 = __builtin_amdgcn_mfma_f32_16x16x32_bf16(b[ks][1], a[ks], acc1, 0, 0, 0);
                }
                float nm[2][4], dn[2][4];
#pragma unroll
                for (int j = 0; j < 2; ++j) {
                    int c0 = (wv * 2 + j) * 16 + kg * 4;
                    floatx4 accj = j ? acc1 : acc0;
                    ushortx4 o;
#pragma unroll
                    for (int i = 0; i < 4; ++i) {
                        float en = accj[i] + bv[j][i] + bf2f(dh[j][i]) + bf2f(eh[j][i]);
                        if (STATS) { es[j][i] += en; eq[j][i] += en * en; o[i] = f2bf(en); }
                        float sg = __builtin_amdgcn_rcpf(1.f + __expf(-en));
                        dn[j][i] = sg;
                        nm[j][i] = sg * bf2f(bh[j][i]);
                    }
                    if (STATS) *(ushortx4*)(e_new + (size_t)erow * 128 + c0) = o;
                }
                // segmented inclusive scan over dst-runs across m16 lanes
                int myd = dr;
#pragma unroll
                for (int off = 1; off < 16; off <<= 1) {
                    int od = __shfl_up(myd, off, 16);
                    bool take = (m16 >= off) && (od == myd);
#pragma unroll
                    for (int j = 0; j < 2; ++j)
#pragma unroll
                        for (int i = 0; i < 4; ++i) {
                            float nv = __shfl_up(nm[j][i], off, 16);
                            float dv = __shfl_up(dn[j][i], off, 16);
                            if (take) { nm[j][i] += nv; dn[j][i] += dv; }
                        }
                }
                int nd = __shfl_down(myd, 1, 16);
                bool tail = (m16 == 15) || (nd != myd);
                if (tail) {
#pragma unroll
                    for (int j = 0; j < 2; ++j) {
                        int c0 = (wv * 2 + j) * 16 + kg * 4;
#pragma unroll
                        for (int i = 0; i < 4; ++i) {
                            atomicAdd(&num[(size_t)myd * 128 + c0 + i], nm[j][i]);
                            atomicAdd(&den[(size_t)myd * 128 + c0 + i], dn[j][i]);
                        }
                    }
                }
            }
            __syncthreads();
            cur ^= 1;
        }
    }

    if (STATS) {
        ls[threadIdx.x] = 0.f;
        __syncthreads();
#pragma unroll
        for (int j = 0; j < 2; ++j) {
            int c0 = (wv * 2 + j) * 16 + kg * 4;
#pragma unroll
            for (int i = 0; i < 4; ++i) {
                atomicAdd(&ls[c0 + i], es[j][i]);
                atomicAdd(&ls[128 + c0 + i], eq[j][i]);
            }
        }
        __syncthreads();
        atomicAdd(&sums[256 + threadIdx.x], ls[threadIdx.x]);
    }
}

// ---------------------------------------------------------------------------
// Quad h-GEMM, 16 waves / 1024 threads, symmetric roles:
//   w 0..3: Ah (fp32), w 4..7: Bh16, w 8..11: Dh16, w 12..15: Eh16.
// ---------------------------------------------------------------------------
__global__ __launch_bounds__(1024) void gemm_h4(const float* __restrict__ h_cur,
                                                const unsigned short* __restrict__ WtL,
                                                const float* __restrict__ Abi,
                                                const float* __restrict__ Bbi,
                                                const float* __restrict__ Dbi,
                                                const float* __restrict__ Ebi,
                                                float* __restrict__ AhB,
                                                unsigned short* __restrict__ Bh16,
                                                unsigned short* __restrict__ Dh16,
                                                unsigned short* __restrict__ Eh16,
                                                int nStrips) {
    const int lane = threadIdx.x & 63;
    const int w = threadIdx.x >> 6;    // 0..15
    const int grp = w >> 2;            // 0:A 1:B 2:D 3:E
    const int ntb = (w & 3) * 2;
    const int m16 = lane & 15;
    const int kg = lane >> 4;

    const int slotmap[4] = {0, 1, 3, 4};
    const float* biasmap[4] = {Abi, Bbi, Dbi, Ebi};
    const unsigned short* Wm = WtL + slotmap[grp] * 16384;
    const float* bp = biasmap[grp];

    short8 bf[4][2];
    floatx4 bv[2];
#pragma unroll
    for (int j = 0; j < 2; ++j) {
#pragma unroll
        for (int ks = 0; ks < 4; ++ks)
            bf[ks][j] = *(const short8*)(Wm + ((ntb + j) * 16 + m16) * 128 + ks * 32 + kg * 8);
        bv[j] = *(const floatx4*)(bp + (ntb + j) * 16 + kg * 4);
    }

    for (int s = blockIdx.x; s < nStrips; s += gridDim.x) {
        size_t rowBase = ((size_t)s * 16 + m16) * 128;
        short8 a[4];
#pragma unroll
        for (int ks = 0; ks < 4; ++ks) {
            int off = ks * 32 + kg * 8;
            floatx4 f0 = *(const floatx4*)(h_cur + rowBase + off);
            floatx4 f1 = *(const floatx4*)(h_cur + rowBase + off + 4);
            short8 t;
            t[0] = (short)f2bf(f0[0]); t[1] = (short)f2bf(f0[1]);
            t[2] = (short)f2bf(f0[2]); t[3] = (short)f2bf(f0[3]);
            t[4] = (short)f2bf(f1[0]); t[5] = (short)f2bf(f1[1]);
            t[6] = (short)f2bf(f1[2]); t[7] = (short)f2bf(f1[3]);
            a[ks] = t;
        }

        floatx4 acc0 = (floatx4){0.f, 0.f, 0.f, 0.f};
        floatx4 acc1 = (floatx4){0.f, 0.f, 0.f, 0.f};
#pragma unroll
        for (int ks = 0; ks < 4; ++ks) {
            acc0 = __builtin_amdgcn_mfma_f32_16x16x32_bf16(bf[ks][0], a[ks], acc0, 0, 0, 0);
            acc1 = __builtin_amdgcn_mfma_f32_16x16x32_bf16(bf[ks][1], a[ks], acc1, 0, 0, 0);
        }

        size_t r = (size_t)s * 16 + m16;
        if (grp == 0) {
            floatx4 o0, o1;
#pragma unroll
            for (int i = 0; i < 4; ++i) { o0[i] = acc0[i] + bv[0][i]; o1[i] = acc1[i] + bv[1][i]; }
            *(floatx4*)(AhB + r * 128 + (ntb + 0) * 16 + kg * 4) = o0;
            *(floatx4*)(AhB + r * 128 + (ntb + 1) * 16 + kg * 4) = o1;
        } else {
            unsigned short* outp = (grp == 1) ? Bh16 : (grp == 2) ? Dh16 : Eh16;
            ushortx4 o0, o1;
#pragma unroll
            for (int i = 0; i < 4; ++i) {
                o0[i] = f2bf(acc0[i] + bv[0][i]);
                o1[i] = f2bf(acc1[i] + bv[1][i]);
            }
            *(ushortx4*)(outp + r * 128 + (ntb + 0) * 16 + kg * 4) = o0;
            *(ushortx4*)(outp + r * 128 + (ntb + 1) * 16 + kg * 4) = o1;
        }
    }
}

// ---------------------------------------------------------------------------
// Streaming node combine: h_new = Ah + num/(den+eps), h-BN stats.
// ---------------------------------------------------------------------------
__global__ __launch_bounds__(256) void node_combine(const float* __restrict__ Ah,
                                                    const float* __restrict__ num,
                                                    const float* __restrict__ den,
                                                    float* __restrict__ h_new,
                                                    float* __restrict__ sums, int N) {
    const int q = threadIdx.x & 31;
    const int g = threadIdx.x >> 5;
    float hs[4] = {0.f, 0.f, 0.f, 0.f};
    float hq[4] = {0.f, 0.f, 0.f, 0.f};
    for (int d = blockIdx.x * 8 + g; d < N; d += gridDim.x * 8) {
        floatx4 ah = *(const floatx4*)(Ah + (size_t)d * 128 + q * 4);
        floatx4 nm = *(const floatx4*)(num + (size_t)d * 128 + q * 4);
        floatx4 dn = *(const floatx4*)(den + (size_t)d * 128 + q * 4);
        floatx4 out;
#pragma unroll
        for (int k = 0; k < 4; ++k) {
            float v = ah[k] + nm[k] / (dn[k] + 1e-6f);
            out[k] = v;
            hs[k] += v;
            hq[k] += v * v;
        }
        *(floatx4*)(h_new + (size_t)d * 128 + q * 4) = out;
    }
    __shared__ float ls[256];
    ls[threadIdx.x] = 0.f;
    __syncthreads();
#pragma unroll
    for (int k = 0; k < 4; ++k) {
        atomicAdd(&ls[q * 4 + k], hs[k]);
        atomicAdd(&ls[128 + q * 4 + k], hq[k]);
    }
    __syncthreads();
    atomicAdd(&sums[threadIdx.x], ls[threadIdx.x]);
}

// ---------------------------------------------------------------------------
// Finalize BN stats -> affine coefs.
// ---------------------------------------------------------------------------
__global__ void finalize_stats(const float* __restrict__ sums,
                               const float* __restrict__ gh,
                               const float* __restrict__ bh,
                               const float* __restrict__ ge,
                               const float* __restrict__ be,
                               float* __restrict__ coef, int N, int E) {
    int c = threadIdx.x;
    if (c >= 128) return;
    float muh = sums[c] / (float)N;
    float vh = fmaxf(sums[128 + c] / (float)N - muh * muh, 0.f);
    float rsh = rsqrtf(vh + 1e-5f);
    float g = gh[c], bt = bh[c];
    coef[c] = g * rsh;
    coef[128 + c] = bt - g * rsh * muh;
    float mue = sums[256 + c] / (float)E;
    float ve = fmaxf(sums[384 + c] / (float)E - mue * mue, 0.f);
    float rse = rsqrtf(ve + 1e-5f);
    float g2 = ge[c], b2 = be[c];
    coef[256 + c] = g2 * rse;
    coef[384 + c] = b2 - g2 * rse * mue;
}

// ---------------------------------------------------------------------------
// h residual update.
// ---------------------------------------------------------------------------
__global__ __launch_bounds__(256) void h_update(const float* __restrict__ h_new,
                                                const float* __restrict__ coef,
                                                float* __restrict__ h_cur,
                                                float* __restrict__ out, int N) {
    const int c = threadIdx.x & 127;
    float sa = coef[c], sb = coef[128 + c];
    int total = N * 128;
    for (int i = blockIdx.x * blockDim.x + threadIdx.x; i < total; i += gridDim.x * blockDim.x) {
        float v = h_new[i] * sa + sb;
        v = v > 0.f ? v : 0.f;
        float h = h_cur[i] + v;
        h_cur[i] = h;
        if (out) out[i] = h;
    }
}

// ---------------------------------------------------------------------------
// e residual update, vectorized: e_cur += relu(BN(e_new)), 8 bf16/thread/iter.
// ---------------------------------------------------------------------------
__global__ __launch_bounds__(256) void e_update(const unsigned short* __restrict__ e_new,
                                                const float* __restrict__ coef,
                                                unsigned short* __restrict__ e_cur, int E) {
    int total8 = E * 16;  // groups of 8 shorts
    for (int idx = blockIdx.x * blockDim.x + threadIdx.x; idx < total8;
         idx += gridDim.x * blockDim.x) {
        int c8 = (idx & 15) * 8;
        short8 en = *(const short8*)(e_new + (size_t)idx * 8);
        short8 ec = *(const short8*)(e_cur + (size_t)idx * 8);
        floatx4 sa0 = *(const floatx4*)(coef + 256 + c8);
        floatx4 sa1 = *(const floatx4*)(coef + 256 + c8 + 4);
        floatx4 sb0 = *(const floatx4*)(coef + 384 + c8);
        floatx4 sb1 = *(const floatx4*)(coef + 384 + c8 + 4);
        short8 r;
#pragma unroll
        for (int k = 0; k < 8; ++k) {
            float sa = (k < 4) ? sa0[k] : sa1[k - 4];
            float sb = (k < 4) ? sb0[k] : sb1[k - 4];
            float v = bf2f((unsigned short)en[k]) * sa + sb;
            v = v > 0.f ? v : 0.f;
            r[k] = (short)f2bf(bf2f((unsigned short)ec[k]) + v);
        }
        *(short8*)(e_cur + (size_t)idx * 8) = r;
    }
}

extern "C" void kernel_launch(void* const* d_in, const int* in_sizes, int n_in,
                              void* d_out, int out_size, void* d_ws, size_t ws_size,
                              hipStream_t stream) {
    const int N = 20000, E = 256000, L = 4;
    const int NPAD = 20032;  // 313 tiles of 64 rows

    const float* h_in = (const float*)d_in[0];
    const float* e_in = (const float*)d_in[1];
    const int* src = (const int*)d_in[2];
    const int* dst = (const int*)d_in[3];
    const float* Wemb_h = (const float*)d_in[4];
    const float* bemb_h = (const float*)d_in[5];
    const float* Wemb_e = (const float*)d_in[6];
    const float* bemb_e = (const float*)d_in[7];
    const float* Aw = (const float*)d_in[8];
    const float* Abi = (const float*)d_in[9];
    const float* Bw = (const float*)d_in[10];
    const float* Bbi = (const float*)d_in[11];
    const float* Cw = (const float*)d_in[12];
    const float* Cbi = (const float*)d_in[13];
    const float* Dw = (const float*)d_in[14];
    const float* Dbi = (const float*)d_in[15];
    const float* Ew = (const float*)d_in[16];
    const float* Ebi = (const float*)d_in[17];
    const float* gh = (const float*)d_in[18];
    const float* bh = (const float*)d_in[19];
    const float* ge = (const float*)d_in[20];
    const float* be = (const float*)d_in[21];

    char* p = (char*)d_ws;
    auto carve = [&](size_t bytes) {
        void* r = (void*)p;
        p += ((bytes + 255) & ~(size_t)255);
        return r;
    };
    unsigned short* Wt = (unsigned short*)carve((size_t)22 * 16384 * 2);
    float* h_cur = (float*)carve((size_t)NPAD * 128 * 4);                 // padded rows
    unsigned short* e_cur = (unsigned short*)carve((size_t)E * 128 * 2);  // CSR order
    unsigned short* e_new = (unsigned short*)carve((size_t)E * 128 * 2);  // CSR order
    float* AhB = (float*)carve((size_t)N * 128 * 4);
    unsigned short* Bh16 = (unsigned short*)carve((size_t)N * 128 * 2);
    unsigned short* Dh16 = (unsigned short*)carve((size_t)N * 128 * 2);
    unsigned short* Eh16 = (unsigned short*)carve((size_t)N * 128 * 2);
    float* h_newB = (float*)carve((size_t)N * 128 * 4);
    float* numden = (float*)carve((size_t)N * 128 * 4 * 2);               // num | den
    float* sums = (float*)carve(4 * 128 * 4);
    float* coef = (float*)carve(4 * 128 * 4);
    int* deg = (int*)carve((size_t)N * 4);
    int* rowptr = (int*)carve((size_t)(N + 1) * 4);
    int* cursor = (int*)carve((size_t)N * 4);
    int* eix = (int*)carve((size_t)E * 4);
    int* sx = (int*)carve((size_t)E * 4);
    int* dstx = (int*)carve((size_t)E * 4);
    float* num = numden;
    float* den = numden + (size_t)N * 128;

    // ---- CSR build ----
    hipMemsetAsync(deg, 0, (size_t)N * 4, stream);
    deg_count<<<(E + 255) / 256, 256, 0, stream>>>(dst, deg, E);
    scan_rowptr<<<1, 1024, 0, stream>>>(deg, rowptr, cursor, N);
    scatter_edges<<<(E + 255) / 256, 256, 0, stream>>>(src, dst, cursor, eix, sx, dstx, E);

    // weights -> transposed bf16 layout
    transpose_w<<<(22 * 16384 + 255) / 256, 256, 0, stream>>>(Wemb_h, Wemb_e, Aw, Bw, Cw, Dw, Ew, Wt);

    // input embeddings (LDS-staged): h normal; e gathered into CSR order via DMA src
    gemm_lds<1, 0, 0><<<313, 256, 0, stream>>>(h_in, nullptr, Wt + 0 * 16384, bemb_h,
                                               h_cur, 313, N);
    gemm_lds<1, 1, 1><<<1024, 256, 0, stream>>>(e_in, eix, Wt + 1 * 16384, bemb_e,
                                                e_cur, E / 64, E);

    for (int l = 0; l < L; ++l) {
        int last = (l == L - 1);
        hipMemsetAsync(sums, 0, 4 * 128 * 4, stream);
        hipMemsetAsync(numden, 0, (size_t)N * 128 * 4 * 2, stream);
        const unsigned short* WtL = Wt + (size_t)(2 + l * 5) * 16384;
        gemm_h4<<<250, 1024, 0, stream>>>(h_cur, WtL, Abi + l * 128, Bbi + l * 128,
                                          Dbi + l * 128, Ebi + l * 128, AhB, Bh16, Dh16, Eh16,
                                          N / 16);
        // e_new = e_cur@Cw + Cb + Dh[sx] + Eh[dstx]; sigma, num/den, e-stats
        if (!last)
            gemm_ce<1><<<1024, 256, 0, stream>>>(e_cur, WtL + 2 * 16384, Cbi + l * 128,
                                                 sx, dstx, Bh16, Dh16, Eh16, e_new,
                                                 num, den, sums, E / 64);
        else
            gemm_ce<0><<<1024, 256, 0, stream>>>(e_cur, WtL + 2 * 16384, Cbi + l * 128,
                                                 sx, dstx, Bh16, Dh16, Eh16, e_new,
                                                 num, den, sums, E / 64);
        node_combine<<<2500, 256, 0, stream>>>(AhB, num, den, h_newB, sums, N);
        finalize_stats<<<1, 128, 0, stream>>>(sums, gh + l * 128, bh + l * 128, ge + l * 128,
                                              be + l * 128, coef, N, E);
        h_update<<<512, 256, 0, stream>>>(h_newB, coef, h_cur, last ? (float*)d_out : nullptr, N);
        if (!last) e_update<<<2048, 256, 0, stream>>>(e_new, coef, e_cur, E);
    }
}

// Round 5
// 1067.533 us; speedup vs baseline: 1.3834x; 1.3834x over previous
//
#include <hip/hip_runtime.h>
#include <hip/hip_bf16.h>

typedef __attribute__((ext_vector_type(8))) short short8;
typedef __attribute__((ext_vector_type(4))) float floatx4;
typedef __attribute__((ext_vector_type(4))) unsigned short ushortx4;

typedef __attribute__((address_space(3))) unsigned int lds_u32;
typedef __attribute__((address_space(1))) const unsigned int g_u32;

__device__ __forceinline__ float bf2f(unsigned short u) {
    union { float f; unsigned int i; } v; v.i = ((unsigned int)u) << 16; return v.f;
}
__device__ __forceinline__ unsigned short f2bf(float f) {
    union { float f; unsigned int i; } v; v.f = f;
    unsigned int r = v.i + 0x7fffu + ((v.i >> 16) & 1u);
    return (unsigned short)(r >> 16);
}

// ---------------------------------------------------------------------------
// CSR build: degree histogram -> chunked block scan -> scatter.
// ---------------------------------------------------------------------------
__global__ void deg_count(const int* __restrict__ dst, int* __restrict__ deg, int E) {
    int i = blockIdx.x * 256 + threadIdx.x;
    if (i < E) atomicAdd(&deg[dst[i]], 1);
}

__global__ __launch_bounds__(1024) void scan_rowptr(const int* __restrict__ deg,
                                                    int* __restrict__ rowptr,
                                                    int* __restrict__ cursor, int N) {
    const int CH = 20;  // 1024*20 = 20480 >= N
    __shared__ int buf[1024];
    int t = threadIdx.x;
    int base = t * CH;
    int local[CH];
    int tot = 0;
#pragma unroll
    for (int k = 0; k < CH; ++k) {
        int i = base + k;
        int v = (i < N) ? deg[i] : 0;
        local[k] = tot;
        tot += v;
    }
    buf[t] = tot;
    __syncthreads();
    for (int off = 1; off < 1024; off <<= 1) {
        int x = (t >= off) ? buf[t - off] : 0;
        __syncthreads();
        buf[t] += x;
        __syncthreads();
    }
    int excl = buf[t] - tot;
#pragma unroll
    for (int k = 0; k < CH; ++k) {
        int i = base + k;
        if (i < N) { rowptr[i] = excl + local[k]; cursor[i] = excl + local[k]; }
    }
    if (t == 1023) rowptr[N] = buf[1023];
}

__global__ void scatter_edges(const int* __restrict__ src, const int* __restrict__ dst,
                              int* __restrict__ cursor, int* __restrict__ eix,
                              int* __restrict__ sx, int E) {
    int i = blockIdx.x * 256 + threadIdx.x;
    if (i >= E) return;
    int d = dst[i];
    int pos = atomicAdd(&cursor[d], 1);
    eix[pos] = i;
    sx[pos] = src[i];
}

// ---------------------------------------------------------------------------
// Weight pre-transpose + bf16 convert: Wt[slot][n*128+k] = bf16(W[slot][k*128+n])
// ---------------------------------------------------------------------------
__global__ void transpose_w(const float* __restrict__ Wh,
                            const float* __restrict__ We,
                            const float* __restrict__ Aw,
                            const float* __restrict__ Bw,
                            const float* __restrict__ Cw,
                            const float* __restrict__ Dw,
                            const float* __restrict__ Ew,
                            unsigned short* __restrict__ Wt) {
    int i = blockIdx.x * 256 + threadIdx.x;
    const int total = 22 * 16384;
    if (i >= total) return;
    int slot = i >> 14;
    int r = i & 16383;
    int n = r >> 7;
    int k = r & 127;
    const float* srcp;
    if (slot == 0) srcp = Wh;
    else if (slot == 1) srcp = We;
    else {
        int t = slot - 2;
        int l = t / 5, w = t % 5;
        const float* bases[5] = {Aw, Bw, Cw, Dw, Ew};
        srcp = bases[w] + l * 16384;
    }
    Wt[i] = f2bf(srcp[k * 128 + n]);
}

// ---------------------------------------------------------------------------
// LDS-staged streaming GEMM: C[M,128] = A[M,128]@W + bias.
// 64-row tiles staged via global_load_lds, double buffered, XOR-swizzled LDS
// (linear DMA dest + inverse-swizzled GLOBAL source + swizzled ds_read).
// Column-split: wave wv owns cols [wv*32, wv*32+32). Swapped-operand MFMA:
// lane holds 4 contiguous output cols of one row.
// GATHER: per-lane DMA source row remapped through ridx (CSR gather, free).
// ---------------------------------------------------------------------------
template <int IN_F32, int OUT_BF16, int GATHER>
__global__ __launch_bounds__(256) void gemm_lds(const void* __restrict__ Ain,
                                                const int* __restrict__ ridx,
                                                const unsigned short* __restrict__ Wt,
                                                const float* __restrict__ bias,
                                                void* __restrict__ Cout,
                                                int nTiles, int Mrows) {
    constexpr int ROWB = IN_F32 ? 512 : 256;     // bytes per row
    constexpr int RSH = IN_F32 ? 9 : 8;
    constexpr int TILEB = 64 * ROWB;             // 32KB / 16KB
    constexpr int PERW = TILEB / 4;              // bytes staged per wave
    constexpr int ROUNDS = PERW / 1024;          // gl_lds insts per wave
    __shared__ unsigned char smem[2][TILEB];

    const int lane = threadIdx.x & 63;
    const int wv = threadIdx.x >> 6;
    const int m16 = lane & 15;
    const int kg = lane >> 4;

    short8 b[4][2];
#pragma unroll
    for (int j = 0; j < 2; ++j)
#pragma unroll
        for (int ks = 0; ks < 4; ++ks)
            b[ks][j] = *(const short8*)(Wt + ((wv * 2 + j) * 16 + m16) * 128 + ks * 32 + kg * 8);
    floatx4 bv[2];
#pragma unroll
    for (int j = 0; j < 2; ++j)
        bv[j] = *(const floatx4*)(bias + (wv * 2 + j) * 16 + kg * 4);

    const unsigned char* Ab = (const unsigned char*)Ain;

    int t0 = blockIdx.x;
    if (t0 >= nTiles) return;

    auto stage = [&](int bufsel, int t) {
#pragma unroll
        for (int r = 0; r < ROUNDS; ++r) {
            int d = wv * PERW + r * 1024 + lane * 16;   // linear dest byte in tile
            int row = d >> RSH;
            int scol;
            if (IN_F32)
                scol = (d ^ ((row & 3) << 5)) & (ROWB - 1);
            else
                scol = (d ^ ((row & 7) << 4)) & (ROWB - 1);
            int grow = t * 64 + row;
            grow = grow < Mrows ? grow : Mrows - 1;     // clamp tail (h path)
            if (GATHER) grow = ridx[grow];
            const unsigned char* gp = Ab + (size_t)grow * ROWB + scol;
            unsigned char* lp = &smem[bufsel][wv * PERW + r * 1024];  // wave-uniform
            __builtin_amdgcn_global_load_lds((g_u32*)gp, (lds_u32*)lp, 16, 0, 0);
        }
    };

    int cur = 0;
    stage(0, t0);
    __syncthreads();

    for (int t = t0; t < nTiles; t += gridDim.x) {
        int tn = t + gridDim.x;
        if (tn < nTiles) stage(cur ^ 1, tn);   // prefetch overlaps compute

        const unsigned char* sb = smem[cur];
#pragma unroll
        for (int st = 0; st < 4; ++st) {
            short8 a[4];
#pragma unroll
            for (int ks = 0; ks < 4; ++ks) {
                if (IN_F32) {
                    int aoff = (st * 16 + m16) * 512 + ks * 128 + kg * 32;
                    aoff ^= (m16 & 3) << 5;
                    floatx4 f0 = *(const floatx4*)(sb + aoff);
                    floatx4 f1 = *(const floatx4*)(sb + aoff + 16);
                    short8 tt;
                    tt[0] = (short)f2bf(f0[0]); tt[1] = (short)f2bf(f0[1]);
                    tt[2] = (short)f2bf(f0[2]); tt[3] = (short)f2bf(f0[3]);
                    tt[4] = (short)f2bf(f1[0]); tt[5] = (short)f2bf(f1[1]);
                    tt[6] = (short)f2bf(f1[2]); tt[7] = (short)f2bf(f1[3]);
                    a[ks] = tt;
                } else {
                    int aoff = (st * 16 + m16) * 256 + ks * 64 + kg * 16;
                    aoff ^= (m16 & 7) << 4;
                    a[ks] = *(const short8*)(sb + aoff);
                }
            }
            floatx4 acc0 = (floatx4){0.f, 0.f, 0.f, 0.f};
            floatx4 acc1 = (floatx4){0.f, 0.f, 0.f, 0.f};
#pragma unroll
            for (int ks = 0; ks < 4; ++ks) {
                acc0 = __builtin_amdgcn_mfma_f32_16x16x32_bf16(b[ks][0], a[ks], acc0, 0, 0, 0);
                acc1 = __builtin_amdgcn_mfma_f32_16x16x32_bf16(b[ks][1], a[ks], acc1, 0, 0, 0);
            }
            size_t row = (size_t)t * 64 + st * 16 + m16;
#pragma unroll
            for (int j = 0; j < 2; ++j) {
                int c0 = (wv * 2 + j) * 16 + kg * 4;
                floatx4 accj = j ? acc1 : acc0;
                if (OUT_BF16) {
                    ushortx4 o;
#pragma unroll
                    for (int i = 0; i < 4; ++i) o[i] = f2bf(accj[i] + bv[j][i]);
                    *(ushortx4*)((unsigned short*)Cout + row * 128 + c0) = o;
                } else {
                    floatx4 o;
#pragma unroll
                    for (int i = 0; i < 4; ++i) o[i] = accj[i] + bv[j][i];
                    *(floatx4*)((float*)Cout + row * 128 + c0) = o;
                }
            }
        }
        __syncthreads();   // drains DMA for next buf + orders LDS reuse
        cur ^= 1;
    }
}

// ---------------------------------------------------------------------------
// Quad h-GEMM, 16 waves / 1024 threads, column-split roles:
//   w 0..3 : Ah  (fp32 out), w 4..7 : Eh (bf16 out),
//   w 8..15: Bh+Dh (nt = w-8) -> one interleaved 16B short8 store.
// ---------------------------------------------------------------------------
__global__ __launch_bounds__(1024) void gemm_h4(const float* __restrict__ h_cur,
                                                const unsigned short* __restrict__ WtL,
                                                const float* __restrict__ Abi,
                                                const float* __restrict__ Bbi,
                                                const float* __restrict__ Dbi,
                                                const float* __restrict__ Ebi,
                                                float* __restrict__ AhB,
                                                unsigned short* __restrict__ BD16,
                                                unsigned short* __restrict__ Eh16,
                                                int nStrips) {
    const int lane = threadIdx.x & 63;
    const int w = threadIdx.x >> 6;    // 0..15
    const int m16 = lane & 15;
    const int kg = lane >> 4;

    short8 bf[4][2];
    floatx4 bv[2];
    if (w < 8) {
        const int slot = (w < 4) ? 0 : 4;                 // A or E weights
        const float* bp = (w < 4) ? Abi : Ebi;
        const int ntb = (w & 3) * 2;
#pragma unroll
        for (int j = 0; j < 2; ++j) {
#pragma unroll
            for (int ks = 0; ks < 4; ++ks)
                bf[ks][j] = *(const short8*)(WtL + slot * 16384 +
                                             ((ntb + j) * 16 + m16) * 128 + ks * 32 + kg * 8);
            bv[j] = *(const floatx4*)(bp + (ntb + j) * 16 + kg * 4);
        }
    } else {
        const int nt = w - 8;
#pragma unroll
        for (int ks = 0; ks < 4; ++ks) {
            bf[ks][0] = *(const short8*)(WtL + 1 * 16384 + (nt * 16 + m16) * 128 + ks * 32 + kg * 8); // B
            bf[ks][1] = *(const short8*)(WtL + 3 * 16384 + (nt * 16 + m16) * 128 + ks * 32 + kg * 8); // D
        }
        bv[0] = *(const floatx4*)(Bbi + nt * 16 + kg * 4);
        bv[1] = *(const floatx4*)(Dbi + nt * 16 + kg * 4);
    }

    for (int s = blockIdx.x; s < nStrips; s += gridDim.x) {
        size_t rowBase = ((size_t)s * 16 + m16) * 128;
        short8 a[4];
#pragma unroll
        for (int ks = 0; ks < 4; ++ks) {
            int off = ks * 32 + kg * 8;
            floatx4 f0 = *(const floatx4*)(h_cur + rowBase + off);
            floatx4 f1 = *(const floatx4*)(h_cur + rowBase + off + 4);
            short8 t;
            t[0] = (short)f2bf(f0[0]); t[1] = (short)f2bf(f0[1]);
            t[2] = (short)f2bf(f0[2]); t[3] = (short)f2bf(f0[3]);
            t[4] = (short)f2bf(f1[0]); t[5] = (short)f2bf(f1[1]);
            t[6] = (short)f2bf(f1[2]); t[7] = (short)f2bf(f1[3]);
            a[ks] = t;
        }

        floatx4 acc0 = (floatx4){0.f, 0.f, 0.f, 0.f};
        floatx4 acc1 = (floatx4){0.f, 0.f, 0.f, 0.f};
#pragma unroll
        for (int ks = 0; ks < 4; ++ks) {
            acc0 = __builtin_amdgcn_mfma_f32_16x16x32_bf16(bf[ks][0], a[ks], acc0, 0, 0, 0);
            acc1 = __builtin_amdgcn_mfma_f32_16x16x32_bf16(bf[ks][1], a[ks], acc1, 0, 0, 0);
        }

        size_t r = (size_t)s * 16 + m16;
        if (w < 4) {
            const int ntb = (w & 3) * 2;
            floatx4 o0, o1;
#pragma unroll
            for (int i = 0; i < 4; ++i) { o0[i] = acc0[i] + bv[0][i]; o1[i] = acc1[i] + bv[1][i]; }
            *(floatx4*)(AhB + r * 128 + (ntb + 0) * 16 + kg * 4) = o0;
            *(floatx4*)(AhB + r * 128 + (ntb + 1) * 16 + kg * 4) = o1;
        } else if (w < 8) {
            const int ntb = (w & 3) * 2;
            ushortx4 o0, o1;
#pragma unroll
            for (int i = 0; i < 4; ++i) {
                o0[i] = f2bf(acc0[i] + bv[0][i]);
                o1[i] = f2bf(acc1[i] + bv[1][i]);
            }
            *(ushortx4*)(Eh16 + r * 128 + (ntb + 0) * 16 + kg * 4) = o0;
            *(ushortx4*)(Eh16 + r * 128 + (ntb + 1) * 16 + kg * 4) = o1;
        } else {
            const int nt = w - 8;
            short8 o;
#pragma unroll
            for (int i = 0; i < 4; ++i) {
                o[2 * i]     = (short)f2bf(acc0[i] + bv[0][i]);  // Bh even
                o[2 * i + 1] = (short)f2bf(acc1[i] + bv[1][i]);  // Dh odd
            }
            *(short8*)(BD16 + r * 256 + (nt * 16 + kg * 4) * 2) = o;
        }
    }
}

// ---------------------------------------------------------------------------
// Fused gate + CSR aggregation + node combine + BN stats.
// 8-edge software pipeline: issue all sx loads, then 8 Ce loads + 8 BD16
// gathers (16 outstanding VMEM/group), then compute. 32 lanes/node.
// DO_E: write e_new (in place over Ce) + e-BN stats (off for last layer).
// ---------------------------------------------------------------------------
template <int DO_E>
__global__ __launch_bounds__(256) void node_aggregate(unsigned short* __restrict__ Ce,
                                                      const unsigned short* __restrict__ BD16,
                                                      const unsigned short* __restrict__ Eh16,
                                                      const int* __restrict__ rowptr,
                                                      const int* __restrict__ sx,
                                                      const float* __restrict__ Ah,
                                                      float* __restrict__ h_new,
                                                      float* __restrict__ sums, int N) {
    const int q = threadIdx.x & 31;
    const int g = threadIdx.x >> 5;
    float hs[4] = {0.f, 0.f, 0.f, 0.f};
    float hq[4] = {0.f, 0.f, 0.f, 0.f};
    float es[4] = {0.f, 0.f, 0.f, 0.f};
    float eq[4] = {0.f, 0.f, 0.f, 0.f};
    for (int d = blockIdx.x * 8 + g; d < N; d += gridDim.x * 8) {
        int beg = rowptr[d], end = rowptr[d + 1];
        ushortx4 eh4 = *(const ushortx4*)(Eh16 + (size_t)d * 128 + q * 4);
        float ehf[4];
#pragma unroll
        for (int k = 0; k < 4; ++k) ehf[k] = bf2f(eh4[k]);
        float num[4] = {0.f, 0.f, 0.f, 0.f};
        float den[4] = {0.f, 0.f, 0.f, 0.f};
        int j = beg;
        for (; j + 7 < end; j += 8) {
            int sv[8];
#pragma unroll
            for (int u = 0; u < 8; ++u) sv[u] = sx[j + u];
            ushortx4 c[8];
#pragma unroll
            for (int u = 0; u < 8; ++u)
                c[u] = *(const ushortx4*)(Ce + (size_t)(j + u) * 128 + q * 4);
            short8 bd[8];
#pragma unroll
            for (int u = 0; u < 8; ++u)
                bd[u] = *(const short8*)(BD16 + (size_t)sv[u] * 256 + q * 8);
#pragma unroll
            for (int u = 0; u < 8; ++u) {
                ushortx4 o;
#pragma unroll
                for (int k = 0; k < 4; ++k) {
                    float en = bf2f(c[u][k]) + bf2f((unsigned short)bd[u][2 * k + 1]) + ehf[k];
                    if (DO_E) {
                        es[k] += en;
                        eq[k] += en * en;
                        o[k] = f2bf(en);
                    }
                    float sg = __builtin_amdgcn_rcpf(1.f + __expf(-en));
                    den[k] += sg;
                    num[k] += sg * bf2f((unsigned short)bd[u][2 * k]);
                }
                if (DO_E) *(ushortx4*)(Ce + (size_t)(j + u) * 128 + q * 4) = o;
            }
        }
        for (; j < end; ++j) {
            int s0 = sx[j];
            ushortx4 c0 = *(const ushortx4*)(Ce + (size_t)j * 128 + q * 4);
            short8 bd0 = *(const short8*)(BD16 + (size_t)s0 * 256 + q * 8);
            ushortx4 o0;
#pragma unroll
            for (int k = 0; k < 4; ++k) {
                float en0 = bf2f(c0[k]) + bf2f((unsigned short)bd0[2 * k + 1]) + ehf[k];
                if (DO_E) {
                    es[k] += en0;
                    eq[k] += en0 * en0;
                    o0[k] = f2bf(en0);
                }
                float sg0 = __builtin_amdgcn_rcpf(1.f + __expf(-en0));
                den[k] += sg0;
                num[k] += sg0 * bf2f((unsigned short)bd0[2 * k]);
            }
            if (DO_E) *(ushortx4*)(Ce + (size_t)j * 128 + q * 4) = o0;
        }
        floatx4 ah = *(const floatx4*)(Ah + (size_t)d * 128 + q * 4);
        floatx4 out;
#pragma unroll
        for (int k = 0; k < 4; ++k) {
            float v = ah[k] + num[k] / (den[k] + 1e-6f);
            out[k] = v;
            hs[k] += v;
            hq[k] += v * v;
        }
        *(floatx4*)(h_new + (size_t)d * 128 + q * 4) = out;
    }
    __shared__ float ls[512];
    ls[threadIdx.x] = 0.f;
    ls[256 + threadIdx.x] = 0.f;
    __syncthreads();
#pragma unroll
    for (int k = 0; k < 4; ++k) {
        atomicAdd(&ls[q * 4 + k], hs[k]);
        atomicAdd(&ls[128 + q * 4 + k], hq[k]);
        if (DO_E) {
            atomicAdd(&ls[256 + q * 4 + k], es[k]);
            atomicAdd(&ls[384 + q * 4 + k], eq[k]);
        }
    }
    __syncthreads();
    atomicAdd(&sums[threadIdx.x], ls[threadIdx.x]);
    if (DO_E) atomicAdd(&sums[256 + threadIdx.x], ls[256 + threadIdx.x]);
}

// ---------------------------------------------------------------------------
// Finalize BN stats -> affine coefs.
// ---------------------------------------------------------------------------
__global__ void finalize_stats(const float* __restrict__ sums,
                               const float* __restrict__ gh,
                               const float* __restrict__ bh,
                               const float* __restrict__ ge,
                               const float* __restrict__ be,
                               float* __restrict__ coef, int N, int E) {
    int c = threadIdx.x;
    if (c >= 128) return;
    float muh = sums[c] / (float)N;
    float vh = fmaxf(sums[128 + c] / (float)N - muh * muh, 0.f);
    float rsh = rsqrtf(vh + 1e-5f);
    float g = gh[c], bt = bh[c];
    coef[c] = g * rsh;
    coef[128 + c] = bt - g * rsh * muh;
    float mue = sums[256 + c] / (float)E;
    float ve = fmaxf(sums[384 + c] / (float)E - mue * mue, 0.f);
    float rse = rsqrtf(ve + 1e-5f);
    float g2 = ge[c], b2 = be[c];
    coef[256 + c] = g2 * rse;
    coef[384 + c] = b2 - g2 * rse * mue;
}

// ---------------------------------------------------------------------------
// h residual update.
// ---------------------------------------------------------------------------
__global__ __launch_bounds__(256) void h_update(const float* __restrict__ h_new,
                                                const float* __restrict__ coef,
                                                float* __restrict__ h_cur,
                                                float* __restrict__ out, int N) {
    const int c = threadIdx.x & 127;
    float sa = coef[c], sb = coef[128 + c];
    int total = N * 128;
    for (int i = blockIdx.x * blockDim.x + threadIdx.x; i < total; i += gridDim.x * blockDim.x) {
        float v = h_new[i] * sa + sb;
        v = v > 0.f ? v : 0.f;
        float h = h_cur[i] + v;
        h_cur[i] = h;
        if (out) out[i] = h;
    }
}

// ---------------------------------------------------------------------------
// e residual update, vectorized: e_cur += relu(BN(e_new)), 8 bf16/thread/iter.
// ---------------------------------------------------------------------------
__global__ __launch_bounds__(256) void e_update(const unsigned short* __restrict__ e_new,
                                                const float* __restrict__ coef,
                                                unsigned short* __restrict__ e_cur, int E) {
    int total8 = E * 16;  // groups of 8 shorts
    for (int idx = blockIdx.x * blockDim.x + threadIdx.x; idx < total8;
         idx += gridDim.x * blockDim.x) {
        int c8 = (idx & 15) * 8;
        short8 en = *(const short8*)(e_new + (size_t)idx * 8);
        short8 ec = *(const short8*)(e_cur + (size_t)idx * 8);
        floatx4 sa0 = *(const floatx4*)(coef + 256 + c8);
        floatx4 sa1 = *(const floatx4*)(coef + 256 + c8 + 4);
        floatx4 sb0 = *(const floatx4*)(coef + 384 + c8);
        floatx4 sb1 = *(const floatx4*)(coef + 384 + c8 + 4);
        short8 r;
#pragma unroll
        for (int k = 0; k < 8; ++k) {
            float sa = (k < 4) ? sa0[k] : sa1[k - 4];
            float sb = (k < 4) ? sb0[k] : sb1[k - 4];
            float v = bf2f((unsigned short)en[k]) * sa + sb;
            v = v > 0.f ? v : 0.f;
            r[k] = (short)f2bf(bf2f((unsigned short)ec[k]) + v);
        }
        *(short8*)(e_cur + (size_t)idx * 8) = r;
    }
}

extern "C" void kernel_launch(void* const* d_in, const int* in_sizes, int n_in,
                              void* d_out, int out_size, void* d_ws, size_t ws_size,
                              hipStream_t stream) {
    const int N = 20000, E = 256000, L = 4;
    const int NPAD = 20032;  // 313 tiles of 64 rows

    const float* h_in = (const float*)d_in[0];
    const float* e_in = (const float*)d_in[1];
    const int* src = (const int*)d_in[2];
    const int* dst = (const int*)d_in[3];
    const float* Wemb_h = (const float*)d_in[4];
    const float* bemb_h = (const float*)d_in[5];
    const float* Wemb_e = (const float*)d_in[6];
    const float* bemb_e = (const float*)d_in[7];
    const float* Aw = (const float*)d_in[8];
    const float* Abi = (const float*)d_in[9];
    const float* Bw = (const float*)d_in[10];
    const float* Bbi = (const float*)d_in[11];
    const float* Cw = (const float*)d_in[12];
    const float* Cbi = (const float*)d_in[13];
    const float* Dw = (const float*)d_in[14];
    const float* Dbi = (const float*)d_in[15];
    const float* Ew = (const float*)d_in[16];
    const float* Ebi = (const float*)d_in[17];
    const float* gh = (const float*)d_in[18];
    const float* bh = (const float*)d_in[19];
    const float* ge = (const float*)d_in[20];
    const float* be = (const float*)d_in[21];

    char* p = (char*)d_ws;
    auto carve = [&](size_t bytes) {
        void* r = (void*)p;
        p += ((bytes + 255) & ~(size_t)255);
        return r;
    };
    unsigned short* Wt = (unsigned short*)carve((size_t)22 * 16384 * 2);
    float* h_cur = (float*)carve((size_t)NPAD * 128 * 4);                 // padded rows
    unsigned short* e_cur = (unsigned short*)carve((size_t)E * 128 * 2);  // CSR order
    unsigned short* e_new = (unsigned short*)carve((size_t)E * 128 * 2);  // Ce then e_new, CSR
    float* AhB = (float*)carve((size_t)N * 128 * 4);
    unsigned short* BD16 = (unsigned short*)carve((size_t)N * 256 * 2);   // Bh/Dh interleaved
    unsigned short* Eh16 = (unsigned short*)carve((size_t)N * 128 * 2);
    float* h_newB = (float*)carve((size_t)N * 128 * 4);
    float* sums = (float*)carve(4 * 128 * 4);
    float* coef = (float*)carve(4 * 128 * 4);
    int* deg = (int*)carve((size_t)N * 4);
    int* rowptr = (int*)carve((size_t)(N + 1) * 4);
    int* cursor = (int*)carve((size_t)N * 4);
    int* eix = (int*)carve((size_t)E * 4);
    int* sx = (int*)carve((size_t)E * 4);

    // ---- CSR build ----
    hipMemsetAsync(deg, 0, (size_t)N * 4, stream);
    deg_count<<<(E + 255) / 256, 256, 0, stream>>>(dst, deg, E);
    scan_rowptr<<<1, 1024, 0, stream>>>(deg, rowptr, cursor, N);
    scatter_edges<<<(E + 255) / 256, 256, 0, stream>>>(src, dst, cursor, eix, sx, E);

    // weights -> transposed bf16 layout
    transpose_w<<<(22 * 16384 + 255) / 256, 256, 0, stream>>>(Wemb_h, Wemb_e, Aw, Bw, Cw, Dw, Ew, Wt);

    // input embeddings (LDS-staged): h normal; e gathered into CSR order via DMA src
    gemm_lds<1, 0, 0><<<313, 256, 0, stream>>>(h_in, nullptr, Wt + 0 * 16384, bemb_h,
                                               h_cur, 313, N);
    gemm_lds<1, 1, 1><<<1024, 256, 0, stream>>>(e_in, eix, Wt + 1 * 16384, bemb_e,
                                                e_cur, E / 64, E);

    for (int l = 0; l < L; ++l) {
        int last = (l == L - 1);
        hipMemsetAsync(sums, 0, 4 * 128 * 4, stream);
        const unsigned short* WtL = Wt + (size_t)(2 + l * 5) * 16384;
        gemm_h4<<<250, 1024, 0, stream>>>(h_cur, WtL, Abi + l * 128, Bbi + l * 128,
                                          Dbi + l * 128, Ebi + l * 128, AhB, BD16, Eh16,
                                          N / 16);
        // Ce = e_cur @ Cw + Cb   (LDS-staged streaming GEMM, bf16 -> bf16)
        gemm_lds<0, 1, 0><<<1024, 256, 0, stream>>>(e_cur, nullptr, WtL + 2 * 16384,
                                                    Cbi + l * 128, e_new, E / 64, E);
        if (!last)
            node_aggregate<1><<<2500, 256, 0, stream>>>(e_new, BD16, Eh16, rowptr, sx, AhB,
                                                        h_newB, sums, N);
        else
            node_aggregate<0><<<2500, 256, 0, stream>>>(e_new, BD16, Eh16, rowptr, sx, AhB,
                                                        h_newB, sums, N);
        finalize_stats<<<1, 128, 0, stream>>>(sums, gh + l * 128, bh + l * 128, ge + l * 128,
                                              be + l * 128, coef, N, E);
        h_update<<<512, 256, 0, stream>>>(h_newB, coef, h_cur, last ? (float*)d_out : nullptr, N);
        if (!last) e_update<<<2048, 256, 0, stream>>>(e_new, coef, e_cur, E);
    }
}

// Round 6
// 960.145 us; speedup vs baseline: 1.5381x; 1.1118x over previous
//
#include <hip/hip_runtime.h>
#include <hip/hip_bf16.h>

typedef __attribute__((ext_vector_type(8))) short short8;
typedef __attribute__((ext_vector_type(4))) float floatx4;
typedef __attribute__((ext_vector_type(4))) unsigned short ushortx4;

typedef __attribute__((address_space(3))) unsigned int lds_u32;
typedef __attribute__((address_space(1))) const unsigned int g_u32;

__device__ __forceinline__ float bf2f(unsigned short u) {
    union { float f; unsigned int i; } v; v.i = ((unsigned int)u) << 16; return v.f;
}
__device__ __forceinline__ unsigned short f2bf(float f) {
    union { float f; unsigned int i; } v; v.f = f;
    unsigned int r = v.i + 0x7fffu + ((v.i >> 16) & 1u);
    return (unsigned short)(r >> 16);
}

// ---------------------------------------------------------------------------
// CSR build: degree histogram -> chunked block scan -> scatter.
// ---------------------------------------------------------------------------
__global__ void deg_count(const int* __restrict__ dst, int* __restrict__ deg, int E) {
    int i = blockIdx.x * 256 + threadIdx.x;
    if (i < E) atomicAdd(&deg[dst[i]], 1);
}

__global__ __launch_bounds__(1024) void scan_rowptr(const int* __restrict__ deg,
                                                    int* __restrict__ rowptr,
                                                    int* __restrict__ cursor, int N) {
    const int CH = 20;  // 1024*20 = 20480 >= N
    __shared__ int buf[1024];
    int t = threadIdx.x;
    int base = t * CH;
    int local[CH];
    int tot = 0;
#pragma unroll
    for (int k = 0; k < CH; ++k) {
        int i = base + k;
        int v = (i < N) ? deg[i] : 0;
        local[k] = tot;
        tot += v;
    }
    buf[t] = tot;
    __syncthreads();
    for (int off = 1; off < 1024; off <<= 1) {
        int x = (t >= off) ? buf[t - off] : 0;
        __syncthreads();
        buf[t] += x;
        __syncthreads();
    }
    int excl = buf[t] - tot;
#pragma unroll
    for (int k = 0; k < CH; ++k) {
        int i = base + k;
        if (i < N) { rowptr[i] = excl + local[k]; cursor[i] = excl + local[k]; }
    }
    if (t == 1023) rowptr[N] = buf[1023];
}

__global__ void scatter_edges(const int* __restrict__ src, const int* __restrict__ dst,
                              int* __restrict__ cursor, int* __restrict__ eix,
                              int* __restrict__ sx, int* __restrict__ dstx, int E) {
    int i = blockIdx.x * 256 + threadIdx.x;
    if (i >= E) return;
    int d = dst[i];
    int pos = atomicAdd(&cursor[d], 1);
    eix[pos] = i;
    sx[pos] = src[i];
    dstx[pos] = d;
}

// ---------------------------------------------------------------------------
// Weight pre-transpose + bf16 convert: Wt[slot][n*128+k] = bf16(W[slot][k*128+n])
// ---------------------------------------------------------------------------
__global__ void transpose_w(const float* __restrict__ Wh,
                            const float* __restrict__ We,
                            const float* __restrict__ Aw,
                            const float* __restrict__ Bw,
                            const float* __restrict__ Cw,
                            const float* __restrict__ Dw,
                            const float* __restrict__ Ew,
                            unsigned short* __restrict__ Wt) {
    int i = blockIdx.x * 256 + threadIdx.x;
    const int total = 22 * 16384;
    if (i >= total) return;
    int slot = i >> 14;
    int r = i & 16383;
    int n = r >> 7;
    int k = r & 127;
    const float* srcp;
    if (slot == 0) srcp = Wh;
    else if (slot == 1) srcp = We;
    else {
        int t = slot - 2;
        int l = t / 5, w = t % 5;
        const float* bases[5] = {Aw, Bw, Cw, Dw, Ew};
        srcp = bases[w] + l * 16384;
    }
    Wt[i] = f2bf(srcp[k * 128 + n]);
}

// ---------------------------------------------------------------------------
// LDS-staged streaming GEMM: C[M,128] = A[M,128]@W + bias.
// 64-row tiles staged via global_load_lds, double buffered, XOR-swizzled LDS
// (linear DMA dest + inverse-swizzled GLOBAL source + swizzled ds_read).
// Column-split: wave wv owns cols [wv*32, wv*32+32). Swapped-operand MFMA:
// lane holds 4 contiguous output cols of one row.
// GATHER: per-lane DMA source row remapped through ridx (CSR gather, free).
// ---------------------------------------------------------------------------
template <int IN_F32, int OUT_BF16, int GATHER>
__global__ __launch_bounds__(256) void gemm_lds(const void* __restrict__ Ain,
                                                const int* __restrict__ ridx,
                                                const unsigned short* __restrict__ Wt,
                                                const float* __restrict__ bias,
                                                void* __restrict__ Cout,
                                                int nTiles, int Mrows) {
    constexpr int ROWB = IN_F32 ? 512 : 256;     // bytes per row
    constexpr int RSH = IN_F32 ? 9 : 8;
    constexpr int TILEB = 64 * ROWB;             // 32KB / 16KB
    constexpr int PERW = TILEB / 4;              // bytes staged per wave
    constexpr int ROUNDS = PERW / 1024;          // gl_lds insts per wave
    __shared__ unsigned char smem[2][TILEB];

    const int lane = threadIdx.x & 63;
    const int wv = threadIdx.x >> 6;
    const int m16 = lane & 15;
    const int kg = lane >> 4;

    short8 b[4][2];
#pragma unroll
    for (int j = 0; j < 2; ++j)
#pragma unroll
        for (int ks = 0; ks < 4; ++ks)
            b[ks][j] = *(const short8*)(Wt + ((wv * 2 + j) * 16 + m16) * 128 + ks * 32 + kg * 8);
    floatx4 bv[2];
#pragma unroll
    for (int j = 0; j < 2; ++j)
        bv[j] = *(const floatx4*)(bias + (wv * 2 + j) * 16 + kg * 4);

    const unsigned char* Ab = (const unsigned char*)Ain;

    int t0 = blockIdx.x;
    if (t0 >= nTiles) return;

    auto stage = [&](int bufsel, int t) {
#pragma unroll
        for (int r = 0; r < ROUNDS; ++r) {
            int d = wv * PERW + r * 1024 + lane * 16;   // linear dest byte in tile
            int row = d >> RSH;
            int scol;
            if (IN_F32)
                scol = (d ^ ((row & 3) << 5)) & (ROWB - 1);
            else
                scol = (d ^ ((row & 7) << 4)) & (ROWB - 1);
            int grow = t * 64 + row;
            grow = grow < Mrows ? grow : Mrows - 1;     // clamp tail (h path)
            if (GATHER) grow = ridx[grow];
            const unsigned char* gp = Ab + (size_t)grow * ROWB + scol;
            unsigned char* lp = &smem[bufsel][wv * PERW + r * 1024];  // wave-uniform
            __builtin_amdgcn_global_load_lds((g_u32*)gp, (lds_u32*)lp, 16, 0, 0);
        }
    };

    int cur = 0;
    stage(0, t0);
    __syncthreads();

    for (int t = t0; t < nTiles; t += gridDim.x) {
        int tn = t + gridDim.x;
        if (tn < nTiles) stage(cur ^ 1, tn);   // prefetch overlaps compute

        const unsigned char* sb = smem[cur];
#pragma unroll
        for (int st = 0; st < 4; ++st) {
            short8 a[4];
#pragma unroll
            for (int ks = 0; ks < 4; ++ks) {
                if (IN_F32) {
                    int aoff = (st * 16 + m16) * 512 + ks * 128 + kg * 32;
                    aoff ^= (m16 & 3) << 5;
                    floatx4 f0 = *(const floatx4*)(sb + aoff);
                    floatx4 f1 = *(const floatx4*)(sb + aoff + 16);
                    short8 tt;
                    tt[0] = (short)f2bf(f0[0]); tt[1] = (short)f2bf(f0[1]);
                    tt[2] = (short)f2bf(f0[2]); tt[3] = (short)f2bf(f0[3]);
                    tt[4] = (short)f2bf(f1[0]); tt[5] = (short)f2bf(f1[1]);
                    tt[6] = (short)f2bf(f1[2]); tt[7] = (short)f2bf(f1[3]);
                    a[ks] = tt;
                } else {
                    int aoff = (st * 16 + m16) * 256 + ks * 64 + kg * 16;
                    aoff ^= (m16 & 7) << 4;
                    a[ks] = *(const short8*)(sb + aoff);
                }
            }
            floatx4 acc0 = (floatx4){0.f, 0.f, 0.f, 0.f};
            floatx4 acc1 = (floatx4){0.f, 0.f, 0.f, 0.f};
#pragma unroll
            for (int ks = 0; ks < 4; ++ks) {
                acc0 = __builtin_amdgcn_mfma_f32_16x16x32_bf16(b[ks][0], a[ks], acc0, 0, 0, 0);
                acc1 = __builtin_amdgcn_mfma_f32_16x16x32_bf16(b[ks][1], a[ks], acc1, 0, 0, 0);
            }
            size_t row = (size_t)t * 64 + st * 16 + m16;
#pragma unroll
            for (int j = 0; j < 2; ++j) {
                int c0 = (wv * 2 + j) * 16 + kg * 4;
                floatx4 accj = j ? acc1 : acc0;
                if (OUT_BF16) {
                    ushortx4 o;
#pragma unroll
                    for (int i = 0; i < 4; ++i) o[i] = f2bf(accj[i] + bv[j][i]);
                    *(ushortx4*)((unsigned short*)Cout + row * 128 + c0) = o;
                } else {
                    floatx4 o;
#pragma unroll
                    for (int i = 0; i < 4; ++i) o[i] = accj[i] + bv[j][i];
                    *(floatx4*)((float*)Cout + row * 128 + c0) = o;
                }
            }
        }
        __syncthreads();   // drains DMA for next buf + orders LDS reuse
        cur ^= 1;
    }
}

// ---------------------------------------------------------------------------
// Quad h-GEMM, 16 waves / 1024 threads, column-split roles:
//   w 0..3 : Ah  (fp32 out), w 4..7 : Eh (bf16 out),
//   w 8..15: Bh+Dh (nt = w-8) -> one interleaved 16B short8 store.
// ---------------------------------------------------------------------------
__global__ __launch_bounds__(1024) void gemm_h4(const float* __restrict__ h_cur,
                                                const unsigned short* __restrict__ WtL,
                                                const float* __restrict__ Abi,
                                                const float* __restrict__ Bbi,
                                                const float* __restrict__ Dbi,
                                                const float* __restrict__ Ebi,
                                                float* __restrict__ AhB,
                                                unsigned short* __restrict__ BD16,
                                                unsigned short* __restrict__ Eh16,
                                                int nStrips) {
    const int lane = threadIdx.x & 63;
    const int w = threadIdx.x >> 6;    // 0..15
    const int m16 = lane & 15;
    const int kg = lane >> 4;

    short8 bf[4][2];
    floatx4 bv[2];
    if (w < 8) {
        const int slot = (w < 4) ? 0 : 4;                 // A or E weights
        const float* bp = (w < 4) ? Abi : Ebi;
        const int ntb = (w & 3) * 2;
#pragma unroll
        for (int j = 0; j < 2; ++j) {
#pragma unroll
            for (int ks = 0; ks < 4; ++ks)
                bf[ks][j] = *(const short8*)(WtL + slot * 16384 +
                                             ((ntb + j) * 16 + m16) * 128 + ks * 32 + kg * 8);
            bv[j] = *(const floatx4*)(bp + (ntb + j) * 16 + kg * 4);
        }
    } else {
        const int nt = w - 8;
#pragma unroll
        for (int ks = 0; ks < 4; ++ks) {
            bf[ks][0] = *(const short8*)(WtL + 1 * 16384 + (nt * 16 + m16) * 128 + ks * 32 + kg * 8); // B
            bf[ks][1] = *(const short8*)(WtL + 3 * 16384 + (nt * 16 + m16) * 128 + ks * 32 + kg * 8); // D
        }
        bv[0] = *(const floatx4*)(Bbi + nt * 16 + kg * 4);
        bv[1] = *(const floatx4*)(Dbi + nt * 16 + kg * 4);
    }

    for (int s = blockIdx.x; s < nStrips; s += gridDim.x) {
        size_t rowBase = ((size_t)s * 16 + m16) * 128;
        short8 a[4];
#pragma unroll
        for (int ks = 0; ks < 4; ++ks) {
            int off = ks * 32 + kg * 8;
            floatx4 f0 = *(const floatx4*)(h_cur + rowBase + off);
            floatx4 f1 = *(const floatx4*)(h_cur + rowBase + off + 4);
            short8 t;
            t[0] = (short)f2bf(f0[0]); t[1] = (short)f2bf(f0[1]);
            t[2] = (short)f2bf(f0[2]); t[3] = (short)f2bf(f0[3]);
            t[4] = (short)f2bf(f1[0]); t[5] = (short)f2bf(f1[1]);
            t[6] = (short)f2bf(f1[2]); t[7] = (short)f2bf(f1[3]);
            a[ks] = t;
        }

        floatx4 acc0 = (floatx4){0.f, 0.f, 0.f, 0.f};
        floatx4 acc1 = (floatx4){0.f, 0.f, 0.f, 0.f};
#pragma unroll
        for (int ks = 0; ks < 4; ++ks) {
            acc0 = __builtin_amdgcn_mfma_f32_16x16x32_bf16(bf[ks][0], a[ks], acc0, 0, 0, 0);
            acc1 = __builtin_amdgcn_mfma_f32_16x16x32_bf16(bf[ks][1], a[ks], acc1, 0, 0, 0);
        }

        size_t r = (size_t)s * 16 + m16;
        if (w < 4) {
            const int ntb = (w & 3) * 2;
            floatx4 o0, o1;
#pragma unroll
            for (int i = 0; i < 4; ++i) { o0[i] = acc0[i] + bv[0][i]; o1[i] = acc1[i] + bv[1][i]; }
            *(floatx4*)(AhB + r * 128 + (ntb + 0) * 16 + kg * 4) = o0;
            *(floatx4*)(AhB + r * 128 + (ntb + 1) * 16 + kg * 4) = o1;
        } else if (w < 8) {
            const int ntb = (w & 3) * 2;
            ushortx4 o0, o1;
#pragma unroll
            for (int i = 0; i < 4; ++i) {
                o0[i] = f2bf(acc0[i] + bv[0][i]);
                o1[i] = f2bf(acc1[i] + bv[1][i]);
            }
            *(ushortx4*)(Eh16 + r * 128 + (ntb + 0) * 16 + kg * 4) = o0;
            *(ushortx4*)(Eh16 + r * 128 + (ntb + 1) * 16 + kg * 4) = o1;
        } else {
            const int nt = w - 8;
            short8 o;
#pragma unroll
            for (int i = 0; i < 4; ++i) {
                o[2 * i]     = (short)f2bf(acc0[i] + bv[0][i]);  // Bh even
                o[2 * i + 1] = (short)f2bf(acc1[i] + bv[1][i]);  // Dh odd
            }
            *(short8*)(BD16 + r * 256 + (nt * 16 + kg * 4) * 2) = o;
        }
    }
}

// ---------------------------------------------------------------------------
// Gate + CSR aggregation + node combine + BN stats (round-2 structure:
// 2-edge unroll, 32 lanes/node, read-only Ce — NO e_new store; e_update
// recomputes en). DO_E: accumulate e-BN stats (off for last layer).
// ---------------------------------------------------------------------------
template <int DO_E>
__global__ __launch_bounds__(256) void node_aggregate(const unsigned short* __restrict__ Ce,
                                                      const unsigned short* __restrict__ BD16,
                                                      const unsigned short* __restrict__ Eh16,
                                                      const int* __restrict__ rowptr,
                                                      const int* __restrict__ sx,
                                                      const float* __restrict__ Ah,
                                                      float* __restrict__ h_new,
                                                      float* __restrict__ sums, int N) {
    const int q = threadIdx.x & 31;
    const int g = threadIdx.x >> 5;
    float hs[4] = {0.f, 0.f, 0.f, 0.f};
    float hq[4] = {0.f, 0.f, 0.f, 0.f};
    float es[4] = {0.f, 0.f, 0.f, 0.f};
    float eq[4] = {0.f, 0.f, 0.f, 0.f};
    for (int d = blockIdx.x * 8 + g; d < N; d += gridDim.x * 8) {
        int beg = rowptr[d], end = rowptr[d + 1];
        ushortx4 eh4 = *(const ushortx4*)(Eh16 + (size_t)d * 128 + q * 4);
        float ehf[4];
#pragma unroll
        for (int k = 0; k < 4; ++k) ehf[k] = bf2f(eh4[k]);
        float num[4] = {0.f, 0.f, 0.f, 0.f};
        float den[4] = {0.f, 0.f, 0.f, 0.f};
        int j = beg;
        for (; j + 1 < end; j += 2) {
            int s0 = sx[j], s1 = sx[j + 1];
            ushortx4 c0 = *(const ushortx4*)(Ce + (size_t)j * 128 + q * 4);
            ushortx4 c1 = *(const ushortx4*)(Ce + (size_t)(j + 1) * 128 + q * 4);
            short8 bd0 = *(const short8*)(BD16 + (size_t)s0 * 256 + q * 8);
            short8 bd1 = *(const short8*)(BD16 + (size_t)s1 * 256 + q * 8);
#pragma unroll
            for (int k = 0; k < 4; ++k) {
                float en0 = bf2f(c0[k]) + bf2f((unsigned short)bd0[2 * k + 1]) + ehf[k];
                float en1 = bf2f(c1[k]) + bf2f((unsigned short)bd1[2 * k + 1]) + ehf[k];
                if (DO_E) {
                    es[k] += en0 + en1;
                    eq[k] += en0 * en0 + en1 * en1;
                }
                float sg0 = __builtin_amdgcn_rcpf(1.f + __expf(-en0));
                float sg1 = __builtin_amdgcn_rcpf(1.f + __expf(-en1));
                den[k] += sg0 + sg1;
                num[k] += sg0 * bf2f((unsigned short)bd0[2 * k])
                        + sg1 * bf2f((unsigned short)bd1[2 * k]);
            }
        }
        if (j < end) {
            int s0 = sx[j];
            ushortx4 c0 = *(const ushortx4*)(Ce + (size_t)j * 128 + q * 4);
            short8 bd0 = *(const short8*)(BD16 + (size_t)s0 * 256 + q * 8);
#pragma unroll
            for (int k = 0; k < 4; ++k) {
                float en0 = bf2f(c0[k]) + bf2f((unsigned short)bd0[2 * k + 1]) + ehf[k];
                if (DO_E) {
                    es[k] += en0;
                    eq[k] += en0 * en0;
                }
                float sg0 = __builtin_amdgcn_rcpf(1.f + __expf(-en0));
                den[k] += sg0;
                num[k] += sg0 * bf2f((unsigned short)bd0[2 * k]);
            }
        }
        floatx4 ah = *(const floatx4*)(Ah + (size_t)d * 128 + q * 4);
        floatx4 out;
#pragma unroll
        for (int k = 0; k < 4; ++k) {
            float v = ah[k] + num[k] / (den[k] + 1e-6f);
            out[k] = v;
            hs[k] += v;
            hq[k] += v * v;
        }
        *(floatx4*)(h_new + (size_t)d * 128 + q * 4) = out;
    }
    __shared__ float ls[512];
    ls[threadIdx.x] = 0.f;
    ls[256 + threadIdx.x] = 0.f;
    __syncthreads();
#pragma unroll
    for (int k = 0; k < 4; ++k) {
        atomicAdd(&ls[q * 4 + k], hs[k]);
        atomicAdd(&ls[128 + q * 4 + k], hq[k]);
        if (DO_E) {
            atomicAdd(&ls[256 + q * 4 + k], es[k]);
            atomicAdd(&ls[384 + q * 4 + k], eq[k]);
        }
    }
    __syncthreads();
    atomicAdd(&sums[threadIdx.x], ls[threadIdx.x]);
    if (DO_E) atomicAdd(&sums[256 + threadIdx.x], ls[256 + threadIdx.x]);
}

// ---------------------------------------------------------------------------
// Finalize BN stats -> affine coefs.
// ---------------------------------------------------------------------------
__global__ void finalize_stats(const float* __restrict__ sums,
                               const float* __restrict__ gh,
                               const float* __restrict__ bh,
                               const float* __restrict__ ge,
                               const float* __restrict__ be,
                               float* __restrict__ coef, int N, int E) {
    int c = threadIdx.x;
    if (c >= 128) return;
    float muh = sums[c] / (float)N;
    float vh = fmaxf(sums[128 + c] / (float)N - muh * muh, 0.f);
    float rsh = rsqrtf(vh + 1e-5f);
    float g = gh[c], bt = bh[c];
    coef[c] = g * rsh;
    coef[128 + c] = bt - g * rsh * muh;
    float mue = sums[256 + c] / (float)E;
    float ve = fmaxf(sums[384 + c] / (float)E - mue * mue, 0.f);
    float rse = rsqrtf(ve + 1e-5f);
    float g2 = ge[c], b2 = be[c];
    coef[256 + c] = g2 * rse;
    coef[384 + c] = b2 - g2 * rse * mue;
}

// ---------------------------------------------------------------------------
// h residual update.
// ---------------------------------------------------------------------------
__global__ __launch_bounds__(256) void h_update(const float* __restrict__ h_new,
                                                const float* __restrict__ coef,
                                                float* __restrict__ h_cur,
                                                float* __restrict__ out, int N) {
    const int c = threadIdx.x & 127;
    float sa = coef[c], sb = coef[128 + c];
    int total = N * 128;
    for (int i = blockIdx.x * blockDim.x + threadIdx.x; i < total; i += gridDim.x * blockDim.x) {
        float v = h_new[i] * sa + sb;
        v = v > 0.f ? v : 0.f;
        float h = h_cur[i] + v;
        h_cur[i] = h;
        if (out) out[i] = h;
    }
}

// ---------------------------------------------------------------------------
// e residual update with en RECOMPUTE: en = Ce + Dh[sx] + Eh[dstx] (f32,
// same add order as node_aggregate), e_cur += relu(BN(en)). Streaming with
// massive TLP -> the two L2-resident row-gathers per edge are latency-hidden.
// 16 threads/edge, 8 cols each.
// ---------------------------------------------------------------------------
__global__ __launch_bounds__(256) void e_update(const unsigned short* __restrict__ Ce,
                                                const unsigned short* __restrict__ BD16,
                                                const unsigned short* __restrict__ Eh16,
                                                const int* __restrict__ sx,
                                                const int* __restrict__ dstx,
                                                const float* __restrict__ coef,
                                                unsigned short* __restrict__ e_cur, int E) {
    int total8 = E * 16;  // groups of 8 shorts
    for (int idx = blockIdx.x * blockDim.x + threadIdx.x; idx < total8;
         idx += gridDim.x * blockDim.x) {
        int j = idx >> 4;
        int c8 = (idx & 15) * 8;
        int sr = sx[j], dr = dstx[j];
        short8 ce = *(const short8*)(Ce + (size_t)idx * 8);
        short8 ec = *(const short8*)(e_cur + (size_t)idx * 8);
        short8 eh = *(const short8*)(Eh16 + (size_t)dr * 128 + c8);
        short8 bd0 = *(const short8*)(BD16 + (size_t)sr * 256 + c8 * 2);      // cols c8..c8+3
        short8 bd1 = *(const short8*)(BD16 + (size_t)sr * 256 + c8 * 2 + 8);  // cols c8+4..c8+7
        floatx4 sa0 = *(const floatx4*)(coef + 256 + c8);
        floatx4 sa1 = *(const floatx4*)(coef + 256 + c8 + 4);
        floatx4 sb0 = *(const floatx4*)(coef + 384 + c8);
        floatx4 sb1 = *(const floatx4*)(coef + 384 + c8 + 4);
        short8 r;
#pragma unroll
        for (int k = 0; k < 8; ++k) {
            unsigned short dh = (unsigned short)((k < 4) ? bd0[2 * k + 1] : bd1[2 * (k - 4) + 1]);
            float en = bf2f((unsigned short)ce[k]) + bf2f(dh) + bf2f((unsigned short)eh[k]);
            float sa = (k < 4) ? sa0[k] : sa1[k - 4];
            float sb = (k < 4) ? sb0[k] : sb1[k - 4];
            float v = en * sa + sb;
            v = v > 0.f ? v : 0.f;
            r[k] = (short)f2bf(bf2f((unsigned short)ec[k]) + v);
        }
        *(short8*)(e_cur + (size_t)idx * 8) = r;
    }
}

extern "C" void kernel_launch(void* const* d_in, const int* in_sizes, int n_in,
                              void* d_out, int out_size, void* d_ws, size_t ws_size,
                              hipStream_t stream) {
    const int N = 20000, E = 256000, L = 4;
    const int NPAD = 20032;  // 313 tiles of 64 rows

    const float* h_in = (const float*)d_in[0];
    const float* e_in = (const float*)d_in[1];
    const int* src = (const int*)d_in[2];
    const int* dst = (const int*)d_in[3];
    const float* Wemb_h = (const float*)d_in[4];
    const float* bemb_h = (const float*)d_in[5];
    const float* Wemb_e = (const float*)d_in[6];
    const float* bemb_e = (const float*)d_in[7];
    const float* Aw = (const float*)d_in[8];
    const float* Abi = (const float*)d_in[9];
    const float* Bw = (const float*)d_in[10];
    const float* Bbi = (const float*)d_in[11];
    const float* Cw = (const float*)d_in[12];
    const float* Cbi = (const float*)d_in[13];
    const float* Dw = (const float*)d_in[14];
    const float* Dbi = (const float*)d_in[15];
    const float* Ew = (const float*)d_in[16];
    const float* Ebi = (const float*)d_in[17];
    const float* gh = (const float*)d_in[18];
    const float* bh = (const float*)d_in[19];
    const float* ge = (const float*)d_in[20];
    const float* be = (const float*)d_in[21];

    char* p = (char*)d_ws;
    auto carve = [&](size_t bytes) {
        void* r = (void*)p;
        p += ((bytes + 255) & ~(size_t)255);
        return r;
    };
    unsigned short* Wt = (unsigned short*)carve((size_t)22 * 16384 * 2);
    float* h_cur = (float*)carve((size_t)NPAD * 128 * 4);                 // padded rows
    unsigned short* e_cur = (unsigned short*)carve((size_t)E * 128 * 2);  // CSR order
    unsigned short* e_new = (unsigned short*)carve((size_t)E * 128 * 2);  // Ce buffer, CSR
    float* AhB = (float*)carve((size_t)N * 128 * 4);
    unsigned short* BD16 = (unsigned short*)carve((size_t)N * 256 * 2);   // Bh/Dh interleaved
    unsigned short* Eh16 = (unsigned short*)carve((size_t)N * 128 * 2);
    float* h_newB = (float*)carve((size_t)N * 128 * 4);
    float* sums = (float*)carve(4 * 128 * 4);
    float* coef = (float*)carve(4 * 128 * 4);
    int* deg = (int*)carve((size_t)N * 4);
    int* rowptr = (int*)carve((size_t)(N + 1) * 4);
    int* cursor = (int*)carve((size_t)N * 4);
    int* eix = (int*)carve((size_t)E * 4);
    int* sx = (int*)carve((size_t)E * 4);
    int* dstx = (int*)carve((size_t)E * 4);

    // ---- CSR build ----
    hipMemsetAsync(deg, 0, (size_t)N * 4, stream);
    deg_count<<<(E + 255) / 256, 256, 0, stream>>>(dst, deg, E);
    scan_rowptr<<<1, 1024, 0, stream>>>(deg, rowptr, cursor, N);
    scatter_edges<<<(E + 255) / 256, 256, 0, stream>>>(src, dst, cursor, eix, sx, dstx, E);

    // weights -> transposed bf16 layout
    transpose_w<<<(22 * 16384 + 255) / 256, 256, 0, stream>>>(Wemb_h, Wemb_e, Aw, Bw, Cw, Dw, Ew, Wt);

    // input embeddings (LDS-staged): h normal; e gathered into CSR order via DMA src
    gemm_lds<1, 0, 0><<<313, 256, 0, stream>>>(h_in, nullptr, Wt + 0 * 16384, bemb_h,
                                               h_cur, 313, N);
    gemm_lds<1, 1, 1><<<1024, 256, 0, stream>>>(e_in, eix, Wt + 1 * 16384, bemb_e,
                                                e_cur, E / 64, E);

    for (int l = 0; l < L; ++l) {
        int last = (l == L - 1);
        hipMemsetAsync(sums, 0, 4 * 128 * 4, stream);
        const unsigned short* WtL = Wt + (size_t)(2 + l * 5) * 16384;
        gemm_h4<<<250, 1024, 0, stream>>>(h_cur, WtL, Abi + l * 128, Bbi + l * 128,
                                          Dbi + l * 128, Ebi + l * 128, AhB, BD16, Eh16,
                                          N / 16);
        // Ce = e_cur @ Cw + Cb   (LDS-staged streaming GEMM, bf16 -> bf16)
        gemm_lds<0, 1, 0><<<1024, 256, 0, stream>>>(e_cur, nullptr, WtL + 2 * 16384,
                                                    Cbi + l * 128, e_new, E / 64, E);
        if (!last)
            node_aggregate<1><<<1250, 256, 0, stream>>>(e_new, BD16, Eh16, rowptr, sx, AhB,
                                                        h_newB, sums, N);
        else
            node_aggregate<0><<<1250, 256, 0, stream>>>(e_new, BD16, Eh16, rowptr, sx, AhB,
                                                        h_newB, sums, N);
        finalize_stats<<<1, 128, 0, stream>>>(sums, gh + l * 128, bh + l * 128, ge + l * 128,
                                              be + l * 128, coef, N, E);
        h_update<<<512, 256, 0, stream>>>(h_newB, coef, h_cur, last ? (float*)d_out : nullptr, N);
        if (!last) e_update<<<2048, 256, 0, stream>>>(e_new, BD16, Eh16, sx, dstx, coef,
                                                      e_cur, E);
    }
}